// Round 12
// baseline (191.163 us; speedup 1.0000x reference)
//
#include <hip/hip_runtime.h>
#include <cstdint>
#include <cstddef>

#define HID 128
#define SEQL 28
#define INP 28
#define NL 10
#define NC 10
#define BATCH 4096
#define BB 16             // batch rows per block (1 block/CU; r7 settled occupancy)
#define STRD 136          // padded row stride in halfs (272 B, b128-aligned)
#define BUFH (16 * STRD)  // halfs per 16x128 activation buffer (4352 B)

// LDS map (dynamic): O(s,p) = slot 2s+p (s=0..2, slots 0..5); SEQ(t) = slot
// 6+t (t=0..27) -> 34 slots x 4352 B = 147968 B. s3 reads/writes SEQ directly
// (its H = own SEQ(t-1)); s0 reads SEQ (g1/g2) or global x via regs (g0).
// No X slots, no Z slot, no zeroing: t==0 skips the H-MFMA block (h_-1 = 0).
#define NSLOT 34
#define LDS_BYTES (NSLOT * BUFH * 2)

typedef _Float16 half8 __attribute__((ext_vector_type(8)));
typedef _Float16 half4 __attribute__((ext_vector_type(4)));
typedef float    f32x4 __attribute__((ext_vector_type(4)));

// tanh(v) = 1 - 2/(e^{2v}+1) from raw HW ops (5 VALU, 2 trans) — r6 win.
__device__ __forceinline__ float tanh_fast(float v) {
  float e = __builtin_amdgcn_exp2f(v * 2.8853900817779268f);  // e^(2v)
  float r = __builtin_amdgcn_rcpf(e + 1.f);
  return __builtin_fmaf(-2.f, r, 1.f);
}

// Light workgroup barrier: orders LDS (lgkmcnt(0)) but does NOT drain vmcnt.
__device__ __forceinline__ void barrier_light() {
  __builtin_amdgcn_sched_barrier(0);
  asm volatile("s_waitcnt lgkmcnt(0)" ::: "memory");
  __builtin_amdgcn_s_barrier();
  __builtin_amdgcn_sched_barrier(0);
}

// Round-12 = round-11 main loop (converged: 117 us dispatch) with the
// convert_weights pre-kernel FUSED AWAY. Every round showed a stable ~59 us
// gap between bench dur and the rnn_fused dispatch; the controllable part is
// the second launch + its duration + the Wcat/bias global round-trip. Weights
// are now read straight from f32 Wih0/Wih/Whh at each group's register-load
// (f32->f16 cast = same RTN rounding as convert_weights -> bit-identical
// numerics; 655 KB of weights are L2-resident after first touch, so the 3x
// per-block f32 re-read is ~11 us of aggregate L2 traffic, not HBM).
// Weight frag source (wave slot s, layer L=g*4+s, row n = n0+nn*16+lane15):
//   ks 0-3 (L>0):  Wih[(L-1)*128+n][ks*32+quad*8]  (two aligned f32x4)
//   ks 4-7      :  Whh[L*128+n][(ks-4)*32+quad*8]  (two aligned f32x4)
//   L==0: only wf[nn][0] used (x is 28-wide; nki=1 path): same predicated
//         per-lane pattern as load_x (quad==3 upper half -> 0).
//   bias4 = bih + bhh (f32x4, aligned).
// Main loop unchanged from r11: tick tau, pt=tau&1, slot s computes t=tau-s;
//   INb: s==0 ? (g==0 ? reg ax : SEQ(t)) : O(s-1,1-pt)
//   Hb (t>0): s==3 ? SEQ(t-1) : O(s,1-pt);   Ob: s==3 ? SEQ(t) : O(s,pt)
// Hazards (via per-tick barrier): consumer of O(s,pt) reads at tau+1,
// overwrite at tau+2; s0 reads SEQ(t) at tau=t, s3 overwrites at t+3;
// cross-group SEQ ordered by the group __syncthreads.
__global__ __launch_bounds__(512, 2) void rnn_fused(
    const float* __restrict__ x,
    const float* __restrict__ Wih0,
    const float* __restrict__ Wih,
    const float* __restrict__ Whh,
    const float* __restrict__ bih,
    const float* __restrict__ bhh,
    const float* __restrict__ fcW,
    const float* __restrict__ fcb,
    float* __restrict__ out) {
  extern __shared__ __align__(16) _Float16 lds[];

  const int tid    = threadIdx.x;
  const int lane15 = tid & 15;        // batch row m (MFMA D col)
  const int quad   = (tid >> 4) & 3;  // MFMA quad -> n offset quad*4+r
  const int wid    = tid >> 6;
  const int s      = wid >> 1;        // layer slot 0..3
  const int n0     = (wid & 1) * 64;  // n-half
  const int b0     = blockIdx.x * BB;

  const int rdoff = lane15 * STRD + quad * 8;       // act-frag read base
  const int wroff = lane15 * STRD + n0 + quad * 4;  // D write base (+nn*16)

  half8 wf[4][8];     // weights [n-subtile][k-frag] (ks 0-3 = IN, 4-7 = H)
  f32x4 bias4[4];
  half8 axbuf[2];     // s0/g0 x frag ping-pong (indexed by literal pt)

  auto cvt8 = [](f32x4 a, f32x4 b) -> half8 {
    half8 r;
#pragma unroll
    for (int i = 0; i < 4; ++i) { r[i] = (_Float16)a[i]; r[4 + i] = (_Float16)b[i]; }
    return r;
  };

  // per-lane x load in exact B-frag layout: k = quad*8 + i (k>=28 -> 0).
  auto load_x = [&](int t, int sl) {
    const float* xr = x + ((size_t)(b0 + lane15) * SEQL + t) * INP;
    f32x4 xa = *(const f32x4*)(xr + quad * 8);
    f32x4 xb = {0.f, 0.f, 0.f, 0.f};
    if (quad < 3) xb = *(const f32x4*)(xr + quad * 8 + 4);
    axbuf[sl] = cvt8(xa, xb);
  };

  for (int g = 0; g < 3; ++g) {
    const int L = g * 4 + s;  // >= NL -> idle slot (barriers only)
    if (L < NL) {
#pragma unroll
      for (int nn = 0; nn < 4; ++nn) {
        const int n = n0 + nn * 16 + lane15;
        if (L > 0) {
          const float* wi = Wih + ((size_t)(L - 1) * HID + n) * HID + quad * 8;
#pragma unroll
          for (int ks = 0; ks < 4; ++ks)
            wf[nn][ks] = cvt8(*(const f32x4*)(wi + ks * 32),
                              *(const f32x4*)(wi + ks * 32 + 4));
        } else {
          // layer 0: x-width 28; only wf[nn][0] is consumed (nki=1 path)
          const float* w0 = Wih0 + (size_t)n * INP + quad * 8;
          f32x4 wa = *(const f32x4*)w0;
          f32x4 wb = {0.f, 0.f, 0.f, 0.f};
          if (quad < 3) wb = *(const f32x4*)(w0 + 4);
          wf[nn][0] = cvt8(wa, wb);
        }
        const float* wh = Whh + ((size_t)L * HID + n) * HID + quad * 8;
#pragma unroll
        for (int ks = 0; ks < 4; ++ks)
          wf[nn][4 + ks] = cvt8(*(const f32x4*)(wh + ks * 32),
                                *(const f32x4*)(wh + ks * 32 + 4));
        const int bofs = L * HID + n0 + nn * 16 + quad * 4;
        f32x4 b1 = *(const f32x4*)(bih + bofs);
        f32x4 b2 = *(const f32x4*)(bhh + bofs);
#pragma unroll
        for (int i = 0; i < 4; ++i) bias4[nn][i] = b1[i] + b2[i];
      }
    }
    // group barrier: prev group's LDS reads complete before SEQ overwrite
    __syncthreads();
    if (g == 0 && s == 0) load_x(0, 0);

    auto tick = [&](int tau, int pt) {
      barrier_light();
      const int t = tau - s;
      if (L < NL && (unsigned)t < SEQL) {
        _Float16* Ob = (s == 3) ? lds + (size_t)(6 + t) * BUFH
                                : lds + (size_t)(2 * s + pt) * BUFH;
        auto tw = [&](int nn, f32x4 av) {
          half4 o;
#pragma unroll
          for (int r = 0; r < 4; ++r) o[r] = (_Float16)tanh_fast(av[r]);
          *(half4*)(Ob + wroff + nn * 16) = o;
        };
        f32x4 a0 = bias4[0], a1 = bias4[1], a2 = bias4[2], a3 = bias4[3];

        if (g == 0 && s == 0) {
          // layer 0: x-input 32 k-wide, from registers (no LDS staging)
          half8 ax = axbuf[pt];
          a0 = __builtin_amdgcn_mfma_f32_16x16x32_f16(wf[0][0], ax, a0, 0, 0, 0);
          a1 = __builtin_amdgcn_mfma_f32_16x16x32_f16(wf[1][0], ax, a1, 0, 0, 0);
          a2 = __builtin_amdgcn_mfma_f32_16x16x32_f16(wf[2][0], ax, a2, 0, 0, 0);
          a3 = __builtin_amdgcn_mfma_f32_16x16x32_f16(wf[3][0], ax, a3, 0, 0, 0);
          if (t > 0) {
            const _Float16* Hb = lds + (size_t)(1 - pt) * BUFH;  // O(0,1-pt)
            half8 ah[4];
#pragma unroll
            for (int ks = 0; ks < 4; ++ks) ah[ks] = *(const half8*)(Hb + rdoff + ks * 32);
#pragma unroll
            for (int ks = 0; ks < 4; ++ks) {  // 4-wide round-robin
              a0 = __builtin_amdgcn_mfma_f32_16x16x32_f16(wf[0][4 + ks], ah[ks], a0, 0, 0, 0);
              a1 = __builtin_amdgcn_mfma_f32_16x16x32_f16(wf[1][4 + ks], ah[ks], a1, 0, 0, 0);
              a2 = __builtin_amdgcn_mfma_f32_16x16x32_f16(wf[2][4 + ks], ah[ks], a2, 0, 0, 0);
              a3 = __builtin_amdgcn_mfma_f32_16x16x32_f16(wf[3][4 + ks], ah[ks], a3, 0, 0, 0);
            }
          }
          tw(0, a0); tw(1, a1); tw(2, a2); tw(3, a3);
        } else {
          const _Float16* INb = (s == 0) ? lds + (size_t)(6 + t) * BUFH
                                         : lds + (size_t)(2 * (s - 1) + (1 - pt)) * BUFH;
          half8 af[8];
#pragma unroll
          for (int ks = 0; ks < 4; ++ks) af[ks] = *(const half8*)(INb + rdoff + ks * 32);
          if (t > 0) {
            const _Float16* Hb = (s == 3) ? lds + (size_t)(6 + (t - 1)) * BUFH
                                          : lds + (size_t)(2 * s + (1 - pt)) * BUFH;
#pragma unroll
            for (int ks = 0; ks < 4; ++ks) af[4 + ks] = *(const half8*)(Hb + rdoff + ks * 32);
#pragma unroll
            for (int i = 0; i < 8; ++i) {  // 4-wide round-robin, frag-major
              a0 = __builtin_amdgcn_mfma_f32_16x16x32_f16(wf[0][i], af[i], a0, 0, 0, 0);
              a1 = __builtin_amdgcn_mfma_f32_16x16x32_f16(wf[1][i], af[i], a1, 0, 0, 0);
              a2 = __builtin_amdgcn_mfma_f32_16x16x32_f16(wf[2][i], af[i], a2, 0, 0, 0);
              a3 = __builtin_amdgcn_mfma_f32_16x16x32_f16(wf[3][i], af[i], a3, 0, 0, 0);
            }
          } else {
#pragma unroll
            for (int i = 0; i < 4; ++i) {
              a0 = __builtin_amdgcn_mfma_f32_16x16x32_f16(wf[0][i], af[i], a0, 0, 0, 0);
              a1 = __builtin_amdgcn_mfma_f32_16x16x32_f16(wf[1][i], af[i], a1, 0, 0, 0);
              a2 = __builtin_amdgcn_mfma_f32_16x16x32_f16(wf[2][i], af[i], a2, 0, 0, 0);
              a3 = __builtin_amdgcn_mfma_f32_16x16x32_f16(wf[3][i], af[i], a3, 0, 0, 0);
            }
          }
          tw(0, a0); tw(1, a1); tw(2, a2); tw(3, a3);
        }
      }
      // issue next x load at tick end (consumed next tick -> latency covered)
      if (g == 0 && s == 0 && tau + 1 < SEQL) load_x(tau + 1, 1 - pt);
    };

    const int Tend = (g == 2) ? 28 : 30;  // even; ticks 0..Tend
    for (int tau = 0; tau < Tend; tau += 2) {
      tick(tau, 0);
      tick(tau + 1, 1);
    }
    tick(Tend, 0);
  }
  __syncthreads();

  // --- FC on layer-9 h at t=27: g2 slot1, tau=28 pt=0 -> O(1,0) = slot 2 ---
  if (tid < BB * NC) {
    int c = tid >> 4;
    int b = tid & 15;
    float acc = fcb[c];
    const float* wr = fcW + c * HID;
    const _Float16* hr = lds + 2 * BUFH + b * STRD;
#pragma unroll
    for (int k0 = 0; k0 < HID; k0 += 8) {
      half8 h = *(const half8*)(hr + k0);
      f32x4 w0 = *(const f32x4*)(wr + k0);
      f32x4 w1 = *(const f32x4*)(wr + k0 + 4);
#pragma unroll
      for (int j = 0; j < 4; ++j)
        acc += (float)h[j] * w0[j] + (float)h[j + 4] * w1[j];
    }
    out[(size_t)(b0 + b) * NC + c] = acc;
  }
}

extern "C" void kernel_launch(void* const* d_in, const int* in_sizes, int n_in,
                              void* d_out, int out_size, void* d_ws, size_t ws_size,
                              hipStream_t stream) {
  const float* x    = (const float*)d_in[0];
  const float* Wih0 = (const float*)d_in[1];
  const float* Wih  = (const float*)d_in[2];
  const float* Whh  = (const float*)d_in[3];
  const float* bih  = (const float*)d_in[4];
  const float* bhh  = (const float*)d_in[5];
  const float* fcW  = (const float*)d_in[6];
  const float* fcb  = (const float*)d_in[7];
  float* out = (float*)d_out;
  (void)d_ws; (void)ws_size;  // no workspace needed anymore

  static bool attr_done = false;
  if (!attr_done) {
    hipFuncSetAttribute(reinterpret_cast<const void*>(rnn_fused),
                        hipFuncAttributeMaxDynamicSharedMemorySize, LDS_BYTES);
    attr_done = true;
  }

  rnn_fused<<<dim3(BATCH / BB), dim3(512), LDS_BYTES, stream>>>(
      x, Wih0, Wih, Whh, bih, bhh, fcW, fcb, out);
}

// Round 13
// 173.786 us; speedup vs baseline: 1.1000x; 1.1000x over previous
//
#include <hip/hip_runtime.h>
#include <cstdint>
#include <cstddef>

#define HID 128
#define SEQL 28
#define INP 28
#define NL 10
#define NC 10
#define BATCH 4096
#define BB 16             // batch rows per block (1 block/CU; r7 settled occupancy)
#define STRD 136          // padded row stride in halfs (272 B, b128-aligned)
#define BUFH (16 * STRD)  // halfs per 16x128 activation buffer (4352 B)

// LDS map (dynamic): O(s,p) = slot 2s+p (s=0..2, slots 0..5); SEQ(t) = slot
// 6+t (t=0..27) -> 34 slots x 4352 B = 147968 B. s3 reads/writes SEQ directly
// (its H = own SEQ(t-1)); s0 reads SEQ (g1/g2) or global x via regs (g0).
// No X slots, no Z slot, no zeroing: t==0 skips the H-MFMA block (h_-1 = 0).
#define NSLOT 34
#define LDS_BYTES (NSLOT * BUFH * 2)

typedef _Float16 half8 __attribute__((ext_vector_type(8)));
typedef _Float16 half4 __attribute__((ext_vector_type(4)));
typedef float    f32x4 __attribute__((ext_vector_type(4)));

// ---------------- ws layout (bytes) ----------------
// Wcat : [NL][HID][256] f16 : 655360 @ 0   row n: [Wih(128, l0 zero-padded) | Whh(128)]
// bias : [NL][HID] f32      : 5120   @ 655360   (b_ih + b_hh)
#define WS_WCAT_OFF 0
#define WS_BIAS_OFF 655360

// Vectorized (r13): one half8 of Wcat per thread — two aligned f32x4 loads +
// one 16B store on the copy paths (was 16 scalar loads + 16 scalar stores).
// 40960 threads, grid 160x256. r12 proved the in-main-kernel f32 alternative
// costs +27 us (scattered 16-lane stride-512B reads); this kernel's coalesced
// convert once is the cheaper division of labor.
__global__ void convert_weights(const float* __restrict__ Wih0,
                                const float* __restrict__ Wih,
                                const float* __restrict__ Whh,
                                const float* __restrict__ bih,
                                const float* __restrict__ bhh,
                                _Float16* __restrict__ Wcat,
                                float* __restrict__ bias) {
  int tg = blockIdx.x * blockDim.x + threadIdx.x;
  if (tg >= NL * HID * 32) return;
  int r = tg >> 5, seg = tg & 31;
  int l = r / HID, n = r % HID;
  int k0 = seg * 8;
  half8 v;
  if (l == 0) {
    if (k0 < 32) {          // mixed Wih0 (k<28) / zero-pad (28..31)
#pragma unroll
      for (int i = 0; i < 8; ++i) {
        int k = k0 + i;
        v[i] = (_Float16)((k < INP) ? Wih0[n * INP + k] : 0.f);
      }
    } else if (k0 < HID) {  // zero-pad 32..127
#pragma unroll
      for (int i = 0; i < 8; ++i) v[i] = (_Float16)0.f;
    } else {                // Whh
      const float* src = Whh + (size_t)n * HID + (k0 - HID);
      f32x4 a = *(const f32x4*)src, b = *(const f32x4*)(src + 4);
#pragma unroll
      for (int i = 0; i < 4; ++i) { v[i] = (_Float16)a[i]; v[4 + i] = (_Float16)b[i]; }
    }
  } else {
    const float* src = (k0 < HID)
        ? (Wih + ((size_t)(l - 1) * HID + n) * HID + k0)
        : (Whh + ((size_t)l * HID + n) * HID + (k0 - HID));
    f32x4 a = *(const f32x4*)src, b = *(const f32x4*)(src + 4);
#pragma unroll
    for (int i = 0; i < 4; ++i) { v[i] = (_Float16)a[i]; v[4 + i] = (_Float16)b[i]; }
  }
  *(half8*)(Wcat + (size_t)r * 256 + k0) = v;
  if (seg == 0) bias[r] = bih[r] + bhh[r];
}

// tanh(v) = 1 - 2/(e^{2v}+1) from raw HW ops (5 VALU, 2 trans) — r6 win.
__device__ __forceinline__ float tanh_fast(float v) {
  float e = __builtin_amdgcn_exp2f(v * 2.8853900817779268f);  // e^(2v)
  float r = __builtin_amdgcn_rcpf(e + 1.f);
  return __builtin_fmaf(-2.f, r, 1.f);
}

// Light workgroup barrier: orders LDS (lgkmcnt(0)) but does NOT drain vmcnt.
__device__ __forceinline__ void barrier_light() {
  __builtin_amdgcn_sched_barrier(0);
  asm volatile("s_waitcnt lgkmcnt(0)" ::: "memory");
  __builtin_amdgcn_s_barrier();
  __builtin_amdgcn_sched_barrier(0);
}

// Round-13 main kernel = round-11 verbatim (measured best: 117.5 us dispatch,
// 176.6 us bench). Structure converged across r3-r12: depth-4 pipeline,
// 8 waves (2-wave n-split teams), register-resident weights (252 combined
// regs/wave -> 2 waves/SIMD hard cap, r5/r7), per-tick light barrier (r9
// refuted flags), LDS-resident SEQ (r8), reg-direct x path + no zeroing
// (r10), 4-wide MFMA round-robin (r11), f16 Wcat via separate kernel (r12
// refuted fusion).
// Tick tau, pt=tau&1: slot s computes t=tau-s.
//   INb: s==0 ? (g==0 ? reg ax : SEQ(t)) : O(s-1,1-pt)
//   Hb (t>0): s==3 ? SEQ(t-1) : O(s,1-pt);   Ob: s==3 ? SEQ(t) : O(s,pt)
// Hazards (via per-tick barrier): consumer of O(s,pt) reads at tau+1,
// overwrite at tau+2; s0 reads SEQ(t) at tau=t, s3 overwrites at t+3;
// cross-group SEQ ordered by the group __syncthreads.
__global__ __launch_bounds__(512, 2) void rnn_fused(
    const float* __restrict__ x,
    const _Float16* __restrict__ Wcat,
    const float* __restrict__ bias,
    const float* __restrict__ fcW,
    const float* __restrict__ fcb,
    float* __restrict__ out) {
  extern __shared__ __align__(16) _Float16 lds[];

  const int tid    = threadIdx.x;
  const int lane15 = tid & 15;        // batch row m (MFMA D col)
  const int quad   = (tid >> 4) & 3;  // MFMA quad -> n offset quad*4+r
  const int wid    = tid >> 6;
  const int s      = wid >> 1;        // layer slot 0..3
  const int n0     = (wid & 1) * 64;  // n-half
  const int b0     = blockIdx.x * BB;

  const int rdoff = lane15 * STRD + quad * 8;       // act-frag read base
  const int wroff = lane15 * STRD + n0 + quad * 4;  // D write base (+nn*16)

  half8 wf[4][8];     // weights [n-subtile][k-frag] (ks 0-3 = IN, 4-7 = H)
  f32x4 bias4[4];
  half8 axbuf[2];     // s0/g0 x frag ping-pong (indexed by literal pt)

  // per-lane x load in exact B-frag layout: k = quad*8 + i (k>=28 -> 0).
  auto load_x = [&](int t, int sl) {
    const float* xr = x + ((size_t)(b0 + lane15) * SEQL + t) * INP;
    f32x4 xa = *(const f32x4*)(xr + quad * 8);
    f32x4 xb = {0.f, 0.f, 0.f, 0.f};
    if (quad < 3) xb = *(const f32x4*)(xr + quad * 8 + 4);
    half8 ax;
#pragma unroll
    for (int i = 0; i < 4; ++i) { ax[i] = (_Float16)xa[i]; ax[4 + i] = (_Float16)xb[i]; }
    axbuf[sl] = ax;
  };

  for (int g = 0; g < 3; ++g) {
    const int L = g * 4 + s;  // >= NL -> idle slot (barriers only)
    if (L < NL) {
      const _Float16* Wl = Wcat + (size_t)L * HID * 256;
#pragma unroll
      for (int nn = 0; nn < 4; ++nn) {
#pragma unroll
        for (int ks = 0; ks < 8; ++ks)
          wf[nn][ks] = *(const half8*)(Wl + (size_t)(n0 + nn * 16 + lane15) * 256 + ks * 32 + quad * 8);
        bias4[nn] = *(const f32x4*)(bias + L * HID + n0 + nn * 16 + quad * 4);
      }
    }
    // group barrier: prev group's LDS reads complete before SEQ overwrite
    __syncthreads();
    if (g == 0 && s == 0) load_x(0, 0);

    auto tick = [&](int tau, int pt) {
      barrier_light();
      const int t = tau - s;
      if (L < NL && (unsigned)t < SEQL) {
        _Float16* Ob = (s == 3) ? lds + (size_t)(6 + t) * BUFH
                                : lds + (size_t)(2 * s + pt) * BUFH;
        auto tw = [&](int nn, f32x4 av) {
          half4 o;
#pragma unroll
          for (int r = 0; r < 4; ++r) o[r] = (_Float16)tanh_fast(av[r]);
          *(half4*)(Ob + wroff + nn * 16) = o;
        };
        f32x4 a0 = bias4[0], a1 = bias4[1], a2 = bias4[2], a3 = bias4[3];

        if (g == 0 && s == 0) {
          // layer 0: x-input 32 k-wide, from registers (no LDS staging)
          half8 ax = axbuf[pt];
          a0 = __builtin_amdgcn_mfma_f32_16x16x32_f16(wf[0][0], ax, a0, 0, 0, 0);
          a1 = __builtin_amdgcn_mfma_f32_16x16x32_f16(wf[1][0], ax, a1, 0, 0, 0);
          a2 = __builtin_amdgcn_mfma_f32_16x16x32_f16(wf[2][0], ax, a2, 0, 0, 0);
          a3 = __builtin_amdgcn_mfma_f32_16x16x32_f16(wf[3][0], ax, a3, 0, 0, 0);
          if (t > 0) {
            const _Float16* Hb = lds + (size_t)(1 - pt) * BUFH;  // O(0,1-pt)
            half8 ah[4];
#pragma unroll
            for (int ks = 0; ks < 4; ++ks) ah[ks] = *(const half8*)(Hb + rdoff + ks * 32);
#pragma unroll
            for (int ks = 0; ks < 4; ++ks) {  // 4-wide round-robin
              a0 = __builtin_amdgcn_mfma_f32_16x16x32_f16(wf[0][4 + ks], ah[ks], a0, 0, 0, 0);
              a1 = __builtin_amdgcn_mfma_f32_16x16x32_f16(wf[1][4 + ks], ah[ks], a1, 0, 0, 0);
              a2 = __builtin_amdgcn_mfma_f32_16x16x32_f16(wf[2][4 + ks], ah[ks], a2, 0, 0, 0);
              a3 = __builtin_amdgcn_mfma_f32_16x16x32_f16(wf[3][4 + ks], ah[ks], a3, 0, 0, 0);
            }
          }
          tw(0, a0); tw(1, a1); tw(2, a2); tw(3, a3);
        } else {
          const _Float16* INb = (s == 0) ? lds + (size_t)(6 + t) * BUFH
                                         : lds + (size_t)(2 * (s - 1) + (1 - pt)) * BUFH;
          half8 af[8];
#pragma unroll
          for (int ks = 0; ks < 4; ++ks) af[ks] = *(const half8*)(INb + rdoff + ks * 32);
          if (t > 0) {
            const _Float16* Hb = (s == 3) ? lds + (size_t)(6 + (t - 1)) * BUFH
                                          : lds + (size_t)(2 * s + (1 - pt)) * BUFH;
#pragma unroll
            for (int ks = 0; ks < 4; ++ks) af[4 + ks] = *(const half8*)(Hb + rdoff + ks * 32);
#pragma unroll
            for (int i = 0; i < 8; ++i) {  // 4-wide round-robin, frag-major
              a0 = __builtin_amdgcn_mfma_f32_16x16x32_f16(wf[0][i], af[i], a0, 0, 0, 0);
              a1 = __builtin_amdgcn_mfma_f32_16x16x32_f16(wf[1][i], af[i], a1, 0, 0, 0);
              a2 = __builtin_amdgcn_mfma_f32_16x16x32_f16(wf[2][i], af[i], a2, 0, 0, 0);
              a3 = __builtin_amdgcn_mfma_f32_16x16x32_f16(wf[3][i], af[i], a3, 0, 0, 0);
            }
          } else {
#pragma unroll
            for (int i = 0; i < 4; ++i) {
              a0 = __builtin_amdgcn_mfma_f32_16x16x32_f16(wf[0][i], af[i], a0, 0, 0, 0);
              a1 = __builtin_amdgcn_mfma_f32_16x16x32_f16(wf[1][i], af[i], a1, 0, 0, 0);
              a2 = __builtin_amdgcn_mfma_f32_16x16x32_f16(wf[2][i], af[i], a2, 0, 0, 0);
              a3 = __builtin_amdgcn_mfma_f32_16x16x32_f16(wf[3][i], af[i], a3, 0, 0, 0);
            }
          }
          tw(0, a0); tw(1, a1); tw(2, a2); tw(3, a3);
        }
      }
      // issue next x load at tick end (consumed next tick -> latency covered)
      if (g == 0 && s == 0 && tau + 1 < SEQL) load_x(tau + 1, 1 - pt);
    };

    const int Tend = (g == 2) ? 28 : 30;  // even; ticks 0..Tend
    for (int tau = 0; tau < Tend; tau += 2) {
      tick(tau, 0);
      tick(tau + 1, 1);
    }
    tick(Tend, 0);
  }
  __syncthreads();

  // --- FC on layer-9 h at t=27: g2 slot1, tau=28 pt=0 -> O(1,0) = slot 2 ---
  if (tid < BB * NC) {
    int c = tid >> 4;
    int b = tid & 15;
    float acc = fcb[c];
    const float* wr = fcW + c * HID;
    const _Float16* hr = lds + 2 * BUFH + b * STRD;
#pragma unroll
    for (int k0 = 0; k0 < HID; k0 += 8) {
      half8 h = *(const half8*)(hr + k0);
      f32x4 w0 = *(const f32x4*)(wr + k0);
      f32x4 w1 = *(const f32x4*)(wr + k0 + 4);
#pragma unroll
      for (int j = 0; j < 4; ++j)
        acc += (float)h[j] * w0[j] + (float)h[j + 4] * w1[j];
    }
    out[(size_t)(b0 + b) * NC + c] = acc;
  }
}

extern "C" void kernel_launch(void* const* d_in, const int* in_sizes, int n_in,
                              void* d_out, int out_size, void* d_ws, size_t ws_size,
                              hipStream_t stream) {
  const float* x    = (const float*)d_in[0];
  const float* Wih0 = (const float*)d_in[1];
  const float* Wih  = (const float*)d_in[2];
  const float* Whh  = (const float*)d_in[3];
  const float* bih  = (const float*)d_in[4];
  const float* bhh  = (const float*)d_in[5];
  const float* fcW  = (const float*)d_in[6];
  const float* fcb  = (const float*)d_in[7];
  float* out = (float*)d_out;

  _Float16* Wcat = (_Float16*)((char*)d_ws + WS_WCAT_OFF);
  float*    bs   = (float*)((char*)d_ws + WS_BIAS_OFF);

  static bool attr_done = false;
  if (!attr_done) {
    hipFuncSetAttribute(reinterpret_cast<const void*>(rnn_fused),
                        hipFuncAttributeMaxDynamicSharedMemorySize, LDS_BYTES);
    attr_done = true;
  }

  convert_weights<<<dim3(160), dim3(256), 0, stream>>>(Wih0, Wih, Whh, bih, bhh, Wcat, bs);
  rnn_fused<<<dim3(BATCH / BB), dim3(512), LDS_BYTES, stream>>>(x, Wcat, bs, fcW, fcb, out);
}

// Round 14
// 168.822 us; speedup vs baseline: 1.1323x; 1.0294x over previous
//
#include <hip/hip_runtime.h>
#include <cstdint>
#include <cstddef>

#define HID 128
#define SEQL 28
#define INP 28
#define NL 10
#define NC 10
#define BATCH 4096
#define BB 16             // batch rows per block (1 block/CU; r7 settled occupancy)
#define STRD 136          // padded row stride in halfs (272 B, b128-aligned)
#define BUFH (16 * STRD)  // halfs per 16x128 activation buffer (4352 B)

// LDS map (dynamic): O(s,p) = slot 2s+p (s=0..2, slots 0..5); SEQ(t) = slot
// 6+t (t=0..27) -> 34 slots x 4352 B = 147968 B. In g0/g1, s3 reads/writes
// SEQ directly (its H = own SEQ(t-1)); s0 reads SEQ (g1) or global x (g0).
// In g2 (4-way n-split, see kernel comment): layer8 uses O(0,p), layer9 uses
// O(1,p); SEQ(t)=h7 is read-only. No zeroing: t==0 skips H-MFMAs (h_-1 = 0).
#define NSLOT 34
#define LDS_BYTES (NSLOT * BUFH * 2)

typedef _Float16 half8 __attribute__((ext_vector_type(8)));
typedef _Float16 half4 __attribute__((ext_vector_type(4)));
typedef float    f32x4 __attribute__((ext_vector_type(4)));

// ---------------- ws layout (bytes) ----------------
// Wcat : [NL][HID][256] f16 : 655360 @ 0   row n: [Wih(128, l0 zero-padded) | Whh(128)]
// bias : [NL][HID] f32      : 5120   @ 655360   (b_ih + b_hh)
#define WS_WCAT_OFF 0
#define WS_BIAS_OFF 655360

// Vectorized (r13): one half8 of Wcat per thread — two aligned f32x4 loads +
// one 16B store on the copy paths. 40960 threads, grid 160x256.
__global__ void convert_weights(const float* __restrict__ Wih0,
                                const float* __restrict__ Wih,
                                const float* __restrict__ Whh,
                                const float* __restrict__ bih,
                                const float* __restrict__ bhh,
                                _Float16* __restrict__ Wcat,
                                float* __restrict__ bias) {
  int tg = blockIdx.x * blockDim.x + threadIdx.x;
  if (tg >= NL * HID * 32) return;
  int r = tg >> 5, seg = tg & 31;
  int l = r / HID, n = r % HID;
  int k0 = seg * 8;
  half8 v;
  if (l == 0) {
    if (k0 < 32) {          // mixed Wih0 (k<28) / zero-pad (28..31)
#pragma unroll
      for (int i = 0; i < 8; ++i) {
        int k = k0 + i;
        v[i] = (_Float16)((k < INP) ? Wih0[n * INP + k] : 0.f);
      }
    } else if (k0 < HID) {  // zero-pad 32..127
#pragma unroll
      for (int i = 0; i < 8; ++i) v[i] = (_Float16)0.f;
    } else {                // Whh
      const float* src = Whh + (size_t)n * HID + (k0 - HID);
      f32x4 a = *(const f32x4*)src, b = *(const f32x4*)(src + 4);
#pragma unroll
      for (int i = 0; i < 4; ++i) { v[i] = (_Float16)a[i]; v[4 + i] = (_Float16)b[i]; }
    }
  } else {
    const float* src = (k0 < HID)
        ? (Wih + ((size_t)(l - 1) * HID + n) * HID + k0)
        : (Whh + ((size_t)l * HID + n) * HID + (k0 - HID));
    f32x4 a = *(const f32x4*)src, b = *(const f32x4*)(src + 4);
#pragma unroll
    for (int i = 0; i < 4; ++i) { v[i] = (_Float16)a[i]; v[4 + i] = (_Float16)b[i]; }
  }
  *(half8*)(Wcat + (size_t)r * 256 + k0) = v;
  if (seg == 0) bias[r] = bih[r] + bhh[r];
}

// tanh(v) = 1 - 2/(e^{2v}+1) from raw HW ops (5 VALU, 2 trans) — r6 win.
__device__ __forceinline__ float tanh_fast(float v) {
  float e = __builtin_amdgcn_exp2f(v * 2.8853900817779268f);  // e^(2v)
  float r = __builtin_amdgcn_rcpf(e + 1.f);
  return __builtin_fmaf(-2.f, r, 1.f);
}

// Light workgroup barrier: orders LDS (lgkmcnt(0)) but does NOT drain vmcnt.
__device__ __forceinline__ void barrier_light() {
  __builtin_amdgcn_sched_barrier(0);
  asm volatile("s_waitcnt lgkmcnt(0)" ::: "memory");
  __builtin_amdgcn_s_barrier();
  __builtin_amdgcn_sched_barrier(0);
}

// Round-14 = round-13 g0/g1 (verbatim) + g2 restructured as a 4-WAY n-split:
// previously g2 (layers 8,9; 29 of 91 ticks) left slots 2,3 — 4 of 8 waves —
// idle. Now all 8 waves work: wave wid handles layer 8+(wid>>2), n-slice
// (wid&3)*32 (2 weight subtiles = 64 regs, reusing wf[0..1]); per-cell chain
// halves (16 MFMA + 8 tanh/wave) with 2 active waves/SIMD instead of 1.
// LDS frag reads/tick unchanged (2 cells x 4 waves x 8 = g0/g1's 4x2x8).
// g2 buffering: layer8 -> O(0,p); layer9 IN = O(0,1-pt), H = own O(1,1-pt),
// out -> O(1,pt); SEQ(t)=h7 read-only (written by g1's s3; last write tau=30,
// first g2 read after >=1 barrier). g1->g2 WAR on O(0/1): g1's last O reads
// at tau<=29, g2's first write after 2+ barriers. FC reads O(1,0)=slot 2
// (t=27 written at g2 tau=28, pt=0) — same location as r13.
// g0/g1 (unchanged): tick tau, pt=tau&1, slot s=wid>>1 computes t=tau-s;
//   INb: s==0 ? (g==0 ? reg ax : SEQ(t)) : O(s-1,1-pt)
//   Hb (t>0): s==3 ? SEQ(t-1) : O(s,1-pt);   Ob: s==3 ? SEQ(t) : O(s,pt)
__global__ __launch_bounds__(512, 2) void rnn_fused(
    const float* __restrict__ x,
    const _Float16* __restrict__ Wcat,
    const float* __restrict__ bias,
    const float* __restrict__ fcW,
    const float* __restrict__ fcb,
    float* __restrict__ out) {
  extern __shared__ __align__(16) _Float16 lds[];

  const int tid    = threadIdx.x;
  const int lane15 = tid & 15;        // batch row m (MFMA D col)
  const int quad   = (tid >> 4) & 3;  // MFMA quad -> n offset quad*4+r
  const int wid    = tid >> 6;
  const int s      = wid >> 1;        // layer slot 0..3 (g0/g1)
  const int n0     = (wid & 1) * 64;  // n-half (g0/g1)
  const int b0     = blockIdx.x * BB;

  const int rdoff = lane15 * STRD + quad * 8;       // act-frag read base
  const int wroff = lane15 * STRD + n0 + quad * 4;  // D write base (+nn*16)

  half8 wf[4][8];     // weights [n-subtile][k-frag] (ks 0-3 = IN, 4-7 = H)
  f32x4 bias4[4];
  half8 axbuf[2];     // s0/g0 x frag ping-pong (indexed by literal pt)

  // per-lane x load in exact B-frag layout: k = quad*8 + i (k>=28 -> 0).
  auto load_x = [&](int t, int sl) {
    const float* xr = x + ((size_t)(b0 + lane15) * SEQL + t) * INP;
    f32x4 xa = *(const f32x4*)(xr + quad * 8);
    f32x4 xb = {0.f, 0.f, 0.f, 0.f};
    if (quad < 3) xb = *(const f32x4*)(xr + quad * 8 + 4);
    half8 ax;
#pragma unroll
    for (int i = 0; i < 4; ++i) { ax[i] = (_Float16)xa[i]; ax[4 + i] = (_Float16)xb[i]; }
    axbuf[sl] = ax;
  };

  // ---------------- g0, g1: depth-4, 2-wave n-split teams ----------------
  for (int g = 0; g < 2; ++g) {
    const int L = g * 4 + s;
    {
      const _Float16* Wl = Wcat + (size_t)L * HID * 256;
#pragma unroll
      for (int nn = 0; nn < 4; ++nn) {
#pragma unroll
        for (int ks = 0; ks < 8; ++ks)
          wf[nn][ks] = *(const half8*)(Wl + (size_t)(n0 + nn * 16 + lane15) * 256 + ks * 32 + quad * 8);
        bias4[nn] = *(const f32x4*)(bias + L * HID + n0 + nn * 16 + quad * 4);
      }
    }
    // group barrier: prev group's LDS reads complete before SEQ overwrite
    __syncthreads();
    if (g == 0 && s == 0) load_x(0, 0);

    auto tick = [&](int tau, int pt) {
      barrier_light();
      const int t = tau - s;
      if ((unsigned)t < SEQL) {
        _Float16* Ob = (s == 3) ? lds + (size_t)(6 + t) * BUFH
                                : lds + (size_t)(2 * s + pt) * BUFH;
        auto tw = [&](int nn, f32x4 av) {
          half4 o;
#pragma unroll
          for (int r = 0; r < 4; ++r) o[r] = (_Float16)tanh_fast(av[r]);
          *(half4*)(Ob + wroff + nn * 16) = o;
        };
        f32x4 a0 = bias4[0], a1 = bias4[1], a2 = bias4[2], a3 = bias4[3];

        if (g == 0 && s == 0) {
          // layer 0: x-input 32 k-wide, from registers (no LDS staging)
          half8 ax = axbuf[pt];
          a0 = __builtin_amdgcn_mfma_f32_16x16x32_f16(wf[0][0], ax, a0, 0, 0, 0);
          a1 = __builtin_amdgcn_mfma_f32_16x16x32_f16(wf[1][0], ax, a1, 0, 0, 0);
          a2 = __builtin_amdgcn_mfma_f32_16x16x32_f16(wf[2][0], ax, a2, 0, 0, 0);
          a3 = __builtin_amdgcn_mfma_f32_16x16x32_f16(wf[3][0], ax, a3, 0, 0, 0);
          if (t > 0) {
            const _Float16* Hb = lds + (size_t)(1 - pt) * BUFH;  // O(0,1-pt)
            half8 ah[4];
#pragma unroll
            for (int ks = 0; ks < 4; ++ks) ah[ks] = *(const half8*)(Hb + rdoff + ks * 32);
#pragma unroll
            for (int ks = 0; ks < 4; ++ks) {  // 4-wide round-robin
              a0 = __builtin_amdgcn_mfma_f32_16x16x32_f16(wf[0][4 + ks], ah[ks], a0, 0, 0, 0);
              a1 = __builtin_amdgcn_mfma_f32_16x16x32_f16(wf[1][4 + ks], ah[ks], a1, 0, 0, 0);
              a2 = __builtin_amdgcn_mfma_f32_16x16x32_f16(wf[2][4 + ks], ah[ks], a2, 0, 0, 0);
              a3 = __builtin_amdgcn_mfma_f32_16x16x32_f16(wf[3][4 + ks], ah[ks], a3, 0, 0, 0);
            }
          }
          tw(0, a0); tw(1, a1); tw(2, a2); tw(3, a3);
        } else {
          const _Float16* INb = (s == 0) ? lds + (size_t)(6 + t) * BUFH
                                         : lds + (size_t)(2 * (s - 1) + (1 - pt)) * BUFH;
          half8 af[8];
#pragma unroll
          for (int ks = 0; ks < 4; ++ks) af[ks] = *(const half8*)(INb + rdoff + ks * 32);
          if (t > 0) {
            const _Float16* Hb = (s == 3) ? lds + (size_t)(6 + (t - 1)) * BUFH
                                          : lds + (size_t)(2 * s + (1 - pt)) * BUFH;
#pragma unroll
            for (int ks = 0; ks < 4; ++ks) af[4 + ks] = *(const half8*)(Hb + rdoff + ks * 32);
#pragma unroll
            for (int i = 0; i < 8; ++i) {  // 4-wide round-robin, frag-major
              a0 = __builtin_amdgcn_mfma_f32_16x16x32_f16(wf[0][i], af[i], a0, 0, 0, 0);
              a1 = __builtin_amdgcn_mfma_f32_16x16x32_f16(wf[1][i], af[i], a1, 0, 0, 0);
              a2 = __builtin_amdgcn_mfma_f32_16x16x32_f16(wf[2][i], af[i], a2, 0, 0, 0);
              a3 = __builtin_amdgcn_mfma_f32_16x16x32_f16(wf[3][i], af[i], a3, 0, 0, 0);
            }
          } else {
#pragma unroll
            for (int i = 0; i < 4; ++i) {
              a0 = __builtin_amdgcn_mfma_f32_16x16x32_f16(wf[0][i], af[i], a0, 0, 0, 0);
              a1 = __builtin_amdgcn_mfma_f32_16x16x32_f16(wf[1][i], af[i], a1, 0, 0, 0);
              a2 = __builtin_amdgcn_mfma_f32_16x16x32_f16(wf[2][i], af[i], a2, 0, 0, 0);
              a3 = __builtin_amdgcn_mfma_f32_16x16x32_f16(wf[3][i], af[i], a3, 0, 0, 0);
            }
          }
          tw(0, a0); tw(1, a1); tw(2, a2); tw(3, a3);
        }
      }
      // issue next x load at tick end (consumed next tick -> latency covered)
      if (g == 0 && s == 0 && tau + 1 < SEQL) load_x(tau + 1, 1 - pt);
    };

    for (int tau = 0; tau < 30; tau += 2) {
      tick(tau, 0);
      tick(tau + 1, 1);
    }
    tick(30, 0);
  }

  // ---------------- g2: layers 8,9 as 4-wave n-split (all 8 waves) --------
  {
    const int s2   = wid >> 2;          // 0 -> layer 8, 1 -> layer 9
    const int n0q  = (wid & 3) * 32;    // 32-wide n-slice
    const int L2   = 8 + s2;
    const int wroff2 = lane15 * STRD + n0q + quad * 4;
    {
      const _Float16* Wl = Wcat + (size_t)L2 * HID * 256;
#pragma unroll
      for (int nn = 0; nn < 2; ++nn) {
#pragma unroll
        for (int ks = 0; ks < 8; ++ks)
          wf[nn][ks] = *(const half8*)(Wl + (size_t)(n0q + nn * 16 + lane15) * 256 + ks * 32 + quad * 8);
        bias4[nn] = *(const f32x4*)(bias + L2 * HID + n0q + nn * 16 + quad * 4);
      }
    }
    __syncthreads();

    auto tick2 = [&](int tau, int pt) {
      barrier_light();
      const int t = tau - s2;
      if ((unsigned)t < SEQL) {
        // layer8 (s2=0): IN = SEQ(t)=h7; layer9 (s2=1): IN = O(0,1-pt)
        const _Float16* INb = (s2 == 0) ? lds + (size_t)(6 + t) * BUFH
                                        : lds + (size_t)(1 - pt) * BUFH;
        _Float16* Ob = lds + (size_t)(2 * s2 + pt) * BUFH;
        half8 af[8];
#pragma unroll
        for (int ks = 0; ks < 4; ++ks) af[ks] = *(const half8*)(INb + rdoff + ks * 32);
        f32x4 a0 = bias4[0], a1 = bias4[1];
        if (t > 0) {
          const _Float16* Hb = lds + (size_t)(2 * s2 + (1 - pt)) * BUFH;  // own prev
#pragma unroll
          for (int ks = 0; ks < 4; ++ks) af[4 + ks] = *(const half8*)(Hb + rdoff + ks * 32);
#pragma unroll
          for (int i = 0; i < 8; ++i) {
            a0 = __builtin_amdgcn_mfma_f32_16x16x32_f16(wf[0][i], af[i], a0, 0, 0, 0);
            a1 = __builtin_amdgcn_mfma_f32_16x16x32_f16(wf[1][i], af[i], a1, 0, 0, 0);
          }
        } else {
#pragma unroll
          for (int i = 0; i < 4; ++i) {
            a0 = __builtin_amdgcn_mfma_f32_16x16x32_f16(wf[0][i], af[i], a0, 0, 0, 0);
            a1 = __builtin_amdgcn_mfma_f32_16x16x32_f16(wf[1][i], af[i], a1, 0, 0, 0);
          }
        }
#pragma unroll
        for (int nn = 0; nn < 2; ++nn) {
          f32x4 av = nn ? a1 : a0;
          half4 o;
#pragma unroll
          for (int r = 0; r < 4; ++r) o[r] = (_Float16)tanh_fast(av[r]);
          *(half4*)(Ob + wroff2 + nn * 16) = o;
        }
      }
    };

    for (int tau = 0; tau < 28; tau += 2) {
      tick2(tau, 0);
      tick2(tau + 1, 1);
    }
    tick2(28, 0);
  }
  __syncthreads();

  // --- FC on layer-9 h at t=27: g2 s2=1, tau=28 pt=0 -> O(1,0) = slot 2 ---
  if (tid < BB * NC) {
    int c = tid >> 4;
    int b = tid & 15;
    float acc = fcb[c];
    const float* wr = fcW + c * HID;
    const _Float16* hr = lds + 2 * BUFH + b * STRD;
#pragma unroll
    for (int k0 = 0; k0 < HID; k0 += 8) {
      half8 h = *(const half8*)(hr + k0);
      f32x4 w0 = *(const f32x4*)(wr + k0);
      f32x4 w1 = *(const f32x4*)(wr + k0 + 4);
#pragma unroll
      for (int j = 0; j < 4; ++j)
        acc += (float)h[j] * w0[j] + (float)h[j + 4] * w1[j];
    }
    out[(size_t)(b0 + b) * NC + c] = acc;
  }
}

extern "C" void kernel_launch(void* const* d_in, const int* in_sizes, int n_in,
                              void* d_out, int out_size, void* d_ws, size_t ws_size,
                              hipStream_t stream) {
  const float* x    = (const float*)d_in[0];
  const float* Wih0 = (const float*)d_in[1];
  const float* Wih  = (const float*)d_in[2];
  const float* Whh  = (const float*)d_in[3];
  const float* bih  = (const float*)d_in[4];
  const float* bhh  = (const float*)d_in[5];
  const float* fcW  = (const float*)d_in[6];
  const float* fcb  = (const float*)d_in[7];
  float* out = (float*)d_out;

  _Float16* Wcat = (_Float16*)((char*)d_ws + WS_WCAT_OFF);
  float*    bs   = (float*)((char*)d_ws + WS_BIAS_OFF);

  static bool attr_done = false;
  if (!attr_done) {
    hipFuncSetAttribute(reinterpret_cast<const void*>(rnn_fused),
                        hipFuncAttributeMaxDynamicSharedMemorySize, LDS_BYTES);
    attr_done = true;
  }

  convert_weights<<<dim3(160), dim3(256), 0, stream>>>(Wih0, Wih, Whh, bih, bhh, Wcat, bs);
  rnn_fused<<<dim3(BATCH / BB), dim3(512), LDS_BYTES, stream>>>(x, Wcat, bs, fcW, fcb, out);
}